// Round 2
// baseline (239.377 us; speedup 1.0000x reference)
//
#include <hip/hip_runtime.h>
#include <hip/hip_bf16.h>

typedef __attribute__((ext_vector_type(8))) short bf16x8;
typedef __attribute__((ext_vector_type(4))) float floatx4;

#define B_TOT 4096
#define NKEEP 25
#define DIM 128
#define NH 4
#define HD 32
#define M_TOT (B_TOT * NKEEP)                 // 102400
#define PER_ELEMS ((size_t)B_TOT * NH * NKEEP * HD)  // 13107200
#define SCALE_Q 0.17677669529663687f

__device__ __forceinline__ short f2bs(float f) {
  __hip_bfloat16 h = __float2bfloat16(f);
  return *reinterpret_cast<short*>(&h);
}

// load 8 consecutive fp32, convert to bf16x8 fragment
__device__ __forceinline__ bf16x8 ld8(const float* p) {
  const float4 u = reinterpret_cast<const float4*>(p)[0];
  const float4 v = reinterpret_cast<const float4*>(p)[1];
  bf16x8 r;
  r[0] = f2bs(u.x); r[1] = f2bs(u.y); r[2] = f2bs(u.z); r[3] = f2bs(u.w);
  r[4] = f2bs(v.x); r[5] = f2bs(v.y); r[6] = f2bs(v.z); r[7] = f2bs(v.w);
  return r;
}

// ---------------- Kernel 1: QKV GEMM ----------------
// out[m][o] = sum_k x[m][k] * qkv_w[o][k] + qkv_b[o], split into q(scaled)/k/v
// internal layout [b][h][n][d] bf16. Wave: 64 rows x 96 cols.
__global__ __launch_bounds__(256) void k_qkv(
    const float* __restrict__ x,
    const float* __restrict__ w,
    const float* __restrict__ bias,
    __hip_bfloat16* __restrict__ qs,
    __hip_bfloat16* __restrict__ ks,
    __hip_bfloat16* __restrict__ vs)
{
  const int tid = threadIdx.x;
  const int wv = tid >> 6, l = tid & 63, l16 = l & 15, quad = l >> 4;
  const int rowbase = blockIdx.x * 256 + wv * 64;
  const int obase = blockIdx.y * 96;

  floatx4 zero = {0.f, 0.f, 0.f, 0.f};
  floatx4 acc[4][6];
#pragma unroll
  for (int mt = 0; mt < 4; ++mt)
#pragma unroll
    for (int nt = 0; nt < 6; ++nt) acc[mt][nt] = zero;

#pragma unroll
  for (int kk = 0; kk < 4; ++kk) {
    const int k0 = kk * 32 + quad * 8;
    bf16x8 a[4];
#pragma unroll
    for (int mt = 0; mt < 4; ++mt)
      a[mt] = ld8(x + (size_t)(rowbase + mt * 16 + l16) * DIM + k0);
#pragma unroll
    for (int nt = 0; nt < 6; ++nt) {
      bf16x8 bw = ld8(w + (size_t)(obase + nt * 16 + l16) * DIM + k0);
#pragma unroll
      for (int mt = 0; mt < 4; ++mt)
        acc[mt][nt] = __builtin_amdgcn_mfma_f32_16x16x32_bf16(a[mt], bw, acc[mt][nt], 0, 0, 0);
    }
  }

#pragma unroll
  for (int mt = 0; mt < 4; ++mt) {
#pragma unroll
    for (int r = 0; r < 4; ++r) {
      const int m = rowbase + mt * 16 + quad * 4 + r;
      const int b = m / 25, n = m - b * 25;
#pragma unroll
      for (int nt = 0; nt < 6; ++nt) {
        const int otile = obase + nt * 16;
        const int o = otile + l16;
        float v = acc[mt][nt][r] + bias[o];
        const int t = o >> 7;
        const int h = (o >> 5) & 3;
        const int d = (otile & 31) + l16;
        __hip_bfloat16* dst = (t == 0) ? qs : (t == 1) ? ks : vs;
        if (t == 0) v *= SCALE_Q;
        dst[(((size_t)b * NH + h) * NKEEP + n) * HD + d] = __float2bfloat16(v);
      }
    }
  }
}

// ---------------- Kernel 2: combined bias+mask table ----------------
// comb[g][h][i][j] = bias_table[rel_index[ids[g,i],ids[g,j]]][h]
//                  + mask[g, ids[g,i], ids[g,j]]
__global__ __launch_bounds__(256) void k_comb(
    const float* __restrict__ mask,
    const int* __restrict__ ids,
    const int* __restrict__ rel,
    const float* __restrict__ btab,
    float* __restrict__ comb)
{
  const int e = blockIdx.x * 256 + threadIdx.x;  // 160000 total, exact grid
  const int j = e % 25;
  const int i = (e / 25) % 25;
  const int h = (e / 625) & 3;
  const int g = e / 2500;
  const int ii = ids[g * 25 + i];
  const int jj = ids[g * 25 + j];
  const int ridx = rel[ii * 49 + jj];
  comb[e] = btab[ridx * 4 + h] + mask[((size_t)g * 49 + ii) * 49 + jj];
}

// ---------------- Kernel 3: fused attention ----------------
// One wave per (b, h). S = q k^T (25x25 pad 32), +comb, softmax, O = P V.
__global__ __launch_bounds__(256) void k_attn(
    const __hip_bfloat16* __restrict__ qs,
    const __hip_bfloat16* __restrict__ ks,
    const __hip_bfloat16* __restrict__ vs,
    const float* __restrict__ comb,
    __hip_bfloat16* __restrict__ ao)
{
  __shared__ __align__(16) short P[NH][32 * 48];  // stride 48 keeps 16B-aligned b128 reads
  const int b = blockIdx.x;
  const int tid = threadIdx.x;
  const int h = tid >> 6, l = tid & 63, l16 = l & 15, quad = l >> 4;
  const int g = b & 63;
  const __hip_bfloat16* qb = qs + ((size_t)b * NH + h) * (NKEEP * HD);
  const __hip_bfloat16* kb = ks + ((size_t)b * NH + h) * (NKEEP * HD);
  const __hip_bfloat16* vb = vs + ((size_t)b * NH + h) * (NKEEP * HD);
  const float* cb = comb + ((size_t)g * NH + h) * (NKEEP * NKEEP);

  floatx4 zero = {0.f, 0.f, 0.f, 0.f};
  bf16x8 aq[2], bk[2];
#pragma unroll
  for (int mt = 0; mt < 2; ++mt) {
    int m = mt * 16 + l16; if (m > 24) m = 24;   // clamp pad rows (values unused)
    aq[mt] = *reinterpret_cast<const bf16x8*>(qb + m * HD + quad * 8);
    bk[mt] = *reinterpret_cast<const bf16x8*>(kb + m * HD + quad * 8);
  }
  floatx4 S[2][2];
#pragma unroll
  for (int mt = 0; mt < 2; ++mt)
#pragma unroll
    for (int nt = 0; nt < 2; ++nt)
      S[mt][nt] = __builtin_amdgcn_mfma_f32_16x16x32_bf16(aq[mt], bk[nt], zero, 0, 0, 0);

  // comb add + row softmax. D layout: row m = mt*16+quad*4+r, col n = nt*16+l16.
#pragma unroll
  for (int mt = 0; mt < 2; ++mt) {
    float s[2][4];
#pragma unroll
    for (int nt = 0; nt < 2; ++nt)
#pragma unroll
      for (int r = 0; r < 4; ++r) {
        const int m = mt * 16 + quad * 4 + r;
        const int n = nt * 16 + l16;
        float v = S[mt][nt][r];
        if (n < 25) { if (m < 25) v += cb[m * 25 + n]; }
        else v = -1e30f;
        s[nt][r] = v;
      }
#pragma unroll
    for (int r = 0; r < 4; ++r) {
      float mx = fmaxf(s[0][r], s[1][r]);
#pragma unroll
      for (int off = 1; off < 16; off <<= 1) mx = fmaxf(mx, __shfl_xor(mx, off));
      const float e0 = __expf(s[0][r] - mx);
      const float e1 = __expf(s[1][r] - mx);
      float sm = e0 + e1;
#pragma unroll
      for (int off = 1; off < 16; off <<= 1) sm += __shfl_xor(sm, off);
      const float inv = 1.f / sm;
      const int m = mt * 16 + quad * 4 + r;
      P[h][m * 48 + l16]      = f2bs(e0 * inv);
      P[h][m * 48 + 16 + l16] = f2bs(e1 * inv);
    }
  }
  __syncthreads();

  bf16x8 bv[2], ap[2];
#pragma unroll
  for (int nt = 0; nt < 2; ++nt) {
    const int d = nt * 16 + l16;
    bf16x8 t;
#pragma unroll
    for (int jj = 0; jj < 8; ++jj) {
      int j = quad * 8 + jj; if (j > 24) j = 24;  // P=0 there; clamp for safety
      t[jj] = *reinterpret_cast<const short*>(vb + j * HD + d);
    }
    bv[nt] = t;
    ap[nt] = *reinterpret_cast<const bf16x8*>(&P[h][(nt * 16 + l16) * 48 + quad * 8]);
  }
  floatx4 O[2][2];
#pragma unroll
  for (int mt = 0; mt < 2; ++mt)
#pragma unroll
    for (int nt = 0; nt < 2; ++nt)
      O[mt][nt] = __builtin_amdgcn_mfma_f32_16x16x32_bf16(ap[mt], bv[nt], zero, 0, 0, 0);

#pragma unroll
  for (int mt = 0; mt < 2; ++mt)
#pragma unroll
    for (int r = 0; r < 4; ++r) {
      const int m = mt * 16 + quad * 4 + r;
      if (m < 25) {
#pragma unroll
        for (int nt = 0; nt < 2; ++nt) {
          const int d = nt * 16 + l16;
          ao[((size_t)b * NKEEP + m) * DIM + h * HD + d] = __float2bfloat16(O[mt][nt][r]);
        }
      }
    }
}

// ---------------- Kernel 4: proj GEMM ----------------
__global__ __launch_bounds__(256) void k_proj(
    const __hip_bfloat16* __restrict__ ain,
    const float* __restrict__ w,
    const float* __restrict__ bias,
    float* __restrict__ out)
{
  const int tid = threadIdx.x;
  const int wv = tid >> 6, l = tid & 63, l16 = l & 15, quad = l >> 4;
  const int rowbase = blockIdx.x * 256 + wv * 64;
  const int obase = blockIdx.y * 64;

  floatx4 zero = {0.f, 0.f, 0.f, 0.f};
  floatx4 acc[4][4];
#pragma unroll
  for (int mt = 0; mt < 4; ++mt)
#pragma unroll
    for (int nt = 0; nt < 4; ++nt) acc[mt][nt] = zero;

#pragma unroll
  for (int kk = 0; kk < 4; ++kk) {
    const int k0 = kk * 32 + quad * 8;
    bf16x8 a[4];
#pragma unroll
    for (int mt = 0; mt < 4; ++mt)
      a[mt] = *reinterpret_cast<const bf16x8*>(
          ain + (size_t)(rowbase + mt * 16 + l16) * DIM + k0);
#pragma unroll
    for (int nt = 0; nt < 4; ++nt) {
      bf16x8 bw = ld8(w + (size_t)(obase + nt * 16 + l16) * DIM + k0);
#pragma unroll
      for (int mt = 0; mt < 4; ++mt)
        acc[mt][nt] = __builtin_amdgcn_mfma_f32_16x16x32_bf16(a[mt], bw, acc[mt][nt], 0, 0, 0);
    }
  }

#pragma unroll
  for (int mt = 0; mt < 4; ++mt) {
#pragma unroll
    for (int r = 0; r < 4; ++r) {
      const size_t m = rowbase + mt * 16 + quad * 4 + r;
#pragma unroll
      for (int nt = 0; nt < 4; ++nt) {
        const int o = obase + nt * 16 + l16;
        out[m * DIM + o] = acc[mt][nt][r] + bias[o];
      }
    }
  }
}

extern "C" void kernel_launch(void* const* d_in, const int* in_sizes, int n_in,
                              void* d_out, int out_size, void* d_ws, size_t ws_size,
                              hipStream_t stream) {
  const float* x    = (const float*)d_in[0];
  const float* mask = (const float*)d_in[1];
  const int*   ids  = (const int*)d_in[2];
  const float* qkvw = (const float*)d_in[3];
  const float* qkvb = (const float*)d_in[4];
  const float* pw   = (const float*)d_in[5];
  const float* pb   = (const float*)d_in[6];
  const float* btab = (const float*)d_in[7];
  const int*   rel  = (const int*)d_in[8];

  char* ws = (char*)d_ws;
  __hip_bfloat16* qs = (__hip_bfloat16*)ws;
  __hip_bfloat16* ks = qs + PER_ELEMS;
  __hip_bfloat16* vs = ks + PER_ELEMS;
  __hip_bfloat16* ao = vs + PER_ELEMS;
  float* comb = (float*)(ws + 4 * PER_ELEMS * sizeof(__hip_bfloat16));
  float* out = (float*)d_out;

  k_qkv <<<dim3(M_TOT / 256, 4), 256, 0, stream>>>(x, qkvw, qkvb, qs, ks, vs);
  k_comb<<<dim3(625),            256, 0, stream>>>(mask, ids, rel, btab, comb);
  k_attn<<<dim3(B_TOT),          256, 0, stream>>>(qs, ks, vs, comb, ao);
  k_proj<<<dim3(M_TOT / 256, 2), 256, 0, stream>>>(ao, pw, pb, out);
}

// Round 3
// 228.507 us; speedup vs baseline: 1.0476x; 1.0476x over previous
//
#include <hip/hip_runtime.h>
#include <hip/hip_bf16.h>

typedef __attribute__((ext_vector_type(8))) short bf16x8;
typedef __attribute__((ext_vector_type(4))) float floatx4;

#define B_TOT 4096
#define NKEEP 25
#define DIM 128
#define NH 4
#define HD 32
#define M_TOT (B_TOT * NKEEP)                 // 102400
#define PER_ELEMS ((size_t)B_TOT * NH * NKEEP * HD)  // 13107200
#define SCALE_Q 0.17677669529663687f

__device__ __forceinline__ short f2bs(float f) {
  __hip_bfloat16 h = __float2bfloat16(f);
  return *reinterpret_cast<short*>(&h);
}

// ---------------- Kernel 0: fp32 -> bf16 conversion (x, qkv_w, proj_w) ----
__global__ __launch_bounds__(256) void k_cvt(
    const float* __restrict__ x, const float* __restrict__ w1,
    const float* __restrict__ w2,
    short* __restrict__ xb, short* __restrict__ w1b, short* __restrict__ w2b)
{
  const size_t GX = (size_t)M_TOT * DIM / 4;   // 3,276,800 float4 groups
  const size_t G1 = 3 * DIM * DIM / 4;         // 12,288
  size_t t = (size_t)blockIdx.x * 256 + threadIdx.x;  // grid exactly GX+G1+G2
  const float* src; short* dst; size_t off;
  if (t < GX)           { src = x;  dst = xb;  off = t; }
  else if (t < GX + G1) { src = w1; dst = w1b; off = t - GX; }
  else                  { src = w2; dst = w2b; off = t - GX - G1; }
  float4 v = reinterpret_cast<const float4*>(src)[off];
  short4 s;
  s.x = f2bs(v.x); s.y = f2bs(v.y); s.z = f2bs(v.z); s.w = f2bs(v.w);
  reinterpret_cast<short4*>(dst)[off] = s;
}

// ---------------- Kernel 1: QKV GEMM (pure bf16) ----------------
__global__ __launch_bounds__(256) void k_qkv(
    const short* __restrict__ x,
    const short* __restrict__ w,
    const float* __restrict__ bias,
    __hip_bfloat16* __restrict__ qs,
    __hip_bfloat16* __restrict__ ks,
    __hip_bfloat16* __restrict__ vs)
{
  const int tid = threadIdx.x;
  const int wv = tid >> 6, l = tid & 63, l16 = l & 15, quad = l >> 4;
  const int rowbase = blockIdx.x * 256 + wv * 64;
  const int obase = blockIdx.y * 96;

  floatx4 zero = {0.f, 0.f, 0.f, 0.f};
  floatx4 acc[4][6];
#pragma unroll
  for (int mt = 0; mt < 4; ++mt)
#pragma unroll
    for (int nt = 0; nt < 6; ++nt) acc[mt][nt] = zero;

#pragma unroll
  for (int kk = 0; kk < 4; ++kk) {
    const int k0 = kk * 32 + quad * 8;
    bf16x8 a[4];
#pragma unroll
    for (int mt = 0; mt < 4; ++mt)
      a[mt] = *reinterpret_cast<const bf16x8*>(
          x + (size_t)(rowbase + mt * 16 + l16) * DIM + k0);
#pragma unroll
    for (int nt = 0; nt < 6; ++nt) {
      bf16x8 bw = *reinterpret_cast<const bf16x8*>(
          w + (size_t)(obase + nt * 16 + l16) * DIM + k0);
#pragma unroll
      for (int mt = 0; mt < 4; ++mt)
        acc[mt][nt] = __builtin_amdgcn_mfma_f32_16x16x32_bf16(a[mt], bw, acc[mt][nt], 0, 0, 0);
    }
  }

#pragma unroll
  for (int mt = 0; mt < 4; ++mt) {
#pragma unroll
    for (int r = 0; r < 4; ++r) {
      const int m = rowbase + mt * 16 + quad * 4 + r;
      const int b = m / 25, n = m - b * 25;
#pragma unroll
      for (int nt = 0; nt < 6; ++nt) {
        const int otile = obase + nt * 16;
        const int o = otile + l16;
        float v = acc[mt][nt][r] + bias[o];
        const int t = o >> 7;
        const int h = (o >> 5) & 3;
        const int d = (otile & 31) + l16;
        __hip_bfloat16* dst = (t == 0) ? qs : (t == 1) ? ks : vs;
        if (t == 0) v *= SCALE_Q;
        dst[(((size_t)b * NH + h) * NKEEP + n) * HD + d] = __float2bfloat16(v);
      }
    }
  }
}

// ---------------- Kernel 2: combined bias+mask table ----------------
__global__ __launch_bounds__(256) void k_comb(
    const float* __restrict__ mask,
    const int* __restrict__ ids,
    const int* __restrict__ rel,
    const float* __restrict__ btab,
    float* __restrict__ comb)
{
  const int e = blockIdx.x * 256 + threadIdx.x;  // 160000 total, exact grid
  const int j = e % 25;
  const int i = (e / 25) % 25;
  const int h = (e / 625) & 3;
  const int g = e / 2500;
  const int ii = ids[g * 25 + i];
  const int jj = ids[g * 25 + j];
  const int ridx = rel[ii * 49 + jj];
  comb[e] = btab[ridx * 4 + h] + mask[((size_t)g * 49 + ii) * 49 + jj];
}

// ---------------- Kernel 3: fused attention + proj ----------------
// One wave per (b, h). S = qk^T, +comb, softmax, O = PV -> LDS,
// then proj: out[:, h*32:(h+1)*32] = AO @ pw^T + pb.
__global__ __launch_bounds__(256) void k_attn(
    const __hip_bfloat16* __restrict__ qs,
    const __hip_bfloat16* __restrict__ ks,
    const __hip_bfloat16* __restrict__ vs,
    const float* __restrict__ comb,
    const short* __restrict__ pwb,
    const float* __restrict__ pb,
    float* __restrict__ out)
{
  __shared__ __align__(16) short P[NH][32 * 48];   // P (A-layout src), stride 48
  __shared__ __align__(16) short VT[NH][32 * 40];  // V^T [d][token], stride 40
  __shared__ __align__(16) short AO[32 * 136];     // attn out rows [m][128+8 pad]
  const int b = blockIdx.x;
  const int tid = threadIdx.x;
  const int h = tid >> 6, l = tid & 63, l16 = l & 15, quad = l >> 4;
  const int g = b & 63;
  const __hip_bfloat16* qb = qs + ((size_t)b * NH + h) * (NKEEP * HD);
  const __hip_bfloat16* kb = ks + ((size_t)b * NH + h) * (NKEEP * HD);
  const __hip_bfloat16* vb = vs + ((size_t)b * NH + h) * (NKEEP * HD);
  const float* cb = comb + ((size_t)g * NH + h) * (NKEEP * NKEEP);

  floatx4 zero = {0.f, 0.f, 0.f, 0.f};
  bf16x8 aq[2], bk[2], av[2];
#pragma unroll
  for (int mt = 0; mt < 2; ++mt) {
    const int m = mt * 16 + l16;
    const int mc = m > 24 ? 24 : m;   // clamp pad rows (finite dup values)
    aq[mt] = *reinterpret_cast<const bf16x8*>(qb + mc * HD + quad * 8);
    bk[mt] = *reinterpret_cast<const bf16x8*>(kb + mc * HD + quad * 8);
    av[mt] = *reinterpret_cast<const bf16x8*>(vb + mc * HD + quad * 8);
    // scatter V^T: VT[d][token=m] ; pad tokens 25..31 get finite dups of row 24
#pragma unroll
    for (int jj = 0; jj < 8; ++jj)
      VT[h][(quad * 8 + jj) * 40 + m] = av[mt][jj];
  }

  floatx4 S[2][2];
#pragma unroll
  for (int mt = 0; mt < 2; ++mt)
#pragma unroll
    for (int nt = 0; nt < 2; ++nt)
      S[mt][nt] = __builtin_amdgcn_mfma_f32_16x16x32_bf16(aq[mt], bk[nt], zero, 0, 0, 0);

  // comb add + row softmax. D layout: row m = mt*16+quad*4+r, col n = nt*16+l16.
#pragma unroll
  for (int mt = 0; mt < 2; ++mt) {
    float s[2][4];
#pragma unroll
    for (int nt = 0; nt < 2; ++nt)
#pragma unroll
      for (int r = 0; r < 4; ++r) {
        const int m = mt * 16 + quad * 4 + r;
        const int n = nt * 16 + l16;
        float v = S[mt][nt][r];
        if (n < 25) { if (m < 25) v += cb[m * 25 + n]; }
        else v = -1e30f;   // pad cols -> exp == 0 exactly
        s[nt][r] = v;
      }
#pragma unroll
    for (int r = 0; r < 4; ++r) {
      float mx = fmaxf(s[0][r], s[1][r]);
#pragma unroll
      for (int off = 1; off < 16; off <<= 1) mx = fmaxf(mx, __shfl_xor(mx, off));
      const float e0 = __expf(s[0][r] - mx);
      const float e1 = __expf(s[1][r] - mx);
      float sm = e0 + e1;
#pragma unroll
      for (int off = 1; off < 16; off <<= 1) sm += __shfl_xor(sm, off);
      const float inv = 1.f / sm;
      const int m = mt * 16 + quad * 4 + r;
      P[h][m * 48 + l16]      = f2bs(e0 * inv);
      P[h][m * 48 + 16 + l16] = f2bs(e1 * inv);
    }
  }
  __syncthreads();   // P and VT ready

  bf16x8 bv[2], ap[2];
#pragma unroll
  for (int t = 0; t < 2; ++t) {
    bv[t] = *reinterpret_cast<const bf16x8*>(&VT[h][(t * 16 + l16) * 40 + quad * 8]);
    ap[t] = *reinterpret_cast<const bf16x8*>(&P[h][(t * 16 + l16) * 48 + quad * 8]);
  }
  floatx4 O[2][2];
#pragma unroll
  for (int mt = 0; mt < 2; ++mt)
#pragma unroll
    for (int nt = 0; nt < 2; ++nt)
      O[mt][nt] = __builtin_amdgcn_mfma_f32_16x16x32_bf16(ap[mt], bv[nt], zero, 0, 0, 0);

  // store O into AO rows (zeros for pad rows m>=25 so proj A-frags are clean)
#pragma unroll
  for (int mt = 0; mt < 2; ++mt)
#pragma unroll
    for (int r = 0; r < 4; ++r) {
      const int m = mt * 16 + quad * 4 + r;
#pragma unroll
      for (int nt = 0; nt < 2; ++nt) {
        const int d = h * 32 + nt * 16 + l16;
        AO[m * 136 + d] = (m < 25) ? f2bs(O[mt][nt][r]) : (short)0;
      }
    }
  __syncthreads();   // AO ready

  // proj: wave h computes out cols h*32..h*32+32 for rows 0..24
  floatx4 acc2[2][2];
#pragma unroll
  for (int mt = 0; mt < 2; ++mt)
#pragma unroll
    for (int nt = 0; nt < 2; ++nt) acc2[mt][nt] = zero;

#pragma unroll
  for (int kk = 0; kk < 4; ++kk) {
    const int k0 = kk * 32 + quad * 8;
    bf16x8 a2[2], b2[2];
#pragma unroll
    for (int mt = 0; mt < 2; ++mt)
      a2[mt] = *reinterpret_cast<const bf16x8*>(&AO[(mt * 16 + l16) * 136 + k0]);
#pragma unroll
    for (int nt = 0; nt < 2; ++nt)
      b2[nt] = *reinterpret_cast<const bf16x8*>(
          pwb + (size_t)(h * 32 + nt * 16 + l16) * DIM + k0);
#pragma unroll
    for (int mt = 0; mt < 2; ++mt)
#pragma unroll
      for (int nt = 0; nt < 2; ++nt)
        acc2[mt][nt] = __builtin_amdgcn_mfma_f32_16x16x32_bf16(a2[mt], b2[nt], acc2[mt][nt], 0, 0, 0);
  }

#pragma unroll
  for (int mt = 0; mt < 2; ++mt)
#pragma unroll
    for (int r = 0; r < 4; ++r) {
      const int m = mt * 16 + quad * 4 + r;
      if (m < 25) {
#pragma unroll
        for (int nt = 0; nt < 2; ++nt) {
          const int o = h * 32 + nt * 16 + l16;
          out[((size_t)b * NKEEP + m) * DIM + o] = acc2[mt][nt][r] + pb[o];
        }
      }
    }
}

extern "C" void kernel_launch(void* const* d_in, const int* in_sizes, int n_in,
                              void* d_out, int out_size, void* d_ws, size_t ws_size,
                              hipStream_t stream) {
  const float* x    = (const float*)d_in[0];
  const float* mask = (const float*)d_in[1];
  const int*   ids  = (const int*)d_in[2];
  const float* qkvw = (const float*)d_in[3];
  const float* qkvb = (const float*)d_in[4];
  const float* pw   = (const float*)d_in[5];
  const float* pb   = (const float*)d_in[6];
  const float* btab = (const float*)d_in[7];
  const int*   rel  = (const int*)d_in[8];

  char* ws = (char*)d_ws;
  __hip_bfloat16* qs = (__hip_bfloat16*)ws;
  __hip_bfloat16* ks = qs + PER_ELEMS;
  __hip_bfloat16* vs = ks + PER_ELEMS;
  short* xb   = (short*)(vs + PER_ELEMS);
  short* w1b  = xb + (size_t)M_TOT * DIM;
  short* w2b  = w1b + 3 * DIM * DIM;
  float* comb = (float*)(w2b + DIM * DIM);
  float* out  = (float*)d_out;

  const int cvt_groups = (M_TOT * DIM + 3 * DIM * DIM + DIM * DIM) / 4;  // 3,293,184
  k_cvt <<<dim3(cvt_groups / 256), 256, 0, stream>>>(x, qkvw, pw, xb, w1b, w2b);
  k_comb<<<dim3(625),              256, 0, stream>>>(mask, ids, rel, btab, comb);
  k_qkv <<<dim3(M_TOT / 256, 4),   256, 0, stream>>>(xb, w1b, qkvb, qs, ks, vs);
  k_attn<<<dim3(B_TOT),            256, 0, stream>>>(qs, ks, vs, comb, w2b, pb, out);
}

// Round 4
// 213.888 us; speedup vs baseline: 1.1192x; 1.0683x over previous
//
#include <hip/hip_runtime.h>
#include <hip/hip_bf16.h>

typedef __attribute__((ext_vector_type(8))) short bf16x8;
typedef __attribute__((ext_vector_type(4))) float floatx4;

#define B_TOT 4096
#define NKEEP 25
#define DIM 128
#define NH 4
#define HD 32
#define SCALE_Q 0.17677669529663687f

__device__ __forceinline__ short f2bs(float f) {
  __hip_bfloat16 h = __float2bfloat16(f);
  return *reinterpret_cast<short*>(&h);
}

// ---------------- Kernel A: weight fp32->bf16 (qkv_w 384x128, proj_w 128x128)
__global__ __launch_bounds__(256) void k_cvtw(
    const float* __restrict__ w1, const float* __restrict__ w2,
    short* __restrict__ w1b, short* __restrict__ w2b)
{
  const int t = blockIdx.x * 256 + threadIdx.x;   // 16384 float4 groups exact
  const int G1 = 3 * DIM * DIM / 4;               // 12288
  const float* src; short* dst; int off;
  if (t < G1) { src = w1; dst = w1b; off = t; }
  else        { src = w2; dst = w2b; off = t - G1; }
  float4 v = reinterpret_cast<const float4*>(src)[off];
  short4 s;
  s.x = f2bs(v.x); s.y = f2bs(v.y); s.z = f2bs(v.z); s.w = f2bs(v.w);
  reinterpret_cast<short4*>(dst)[off] = s;
}

// ---------------- Kernel B: combined bias+mask table ----------------
__global__ __launch_bounds__(256) void k_comb(
    const float* __restrict__ mask,
    const int* __restrict__ ids,
    const int* __restrict__ rel,
    const float* __restrict__ btab,
    float* __restrict__ comb)
{
  const int e = blockIdx.x * 256 + threadIdx.x;  // 160000 total, exact grid
  const int j = e % 25;
  const int i = (e / 25) % 25;
  const int h = (e / 625) & 3;
  const int g = e / 2500;
  const int ii = ids[g * 25 + i];
  const int jj = ids[g * 25 + j];
  const int ridx = rel[ii * 49 + jj];
  comb[e] = btab[ridx * 4 + h] + mask[((size_t)g * 49 + ii) * 49 + jj];
}

// ---------------- Kernel C: fully fused QKV + attention + proj ----------
// One block per window b. Wave wv: QKV cols [wv*96,wv*96+96); attention head wv;
// proj cols [wv*32, wv*32+32).
__global__ __launch_bounds__(256, 3) void k_fused(
    const float* __restrict__ x,
    const short* __restrict__ w1b,
    const float* __restrict__ qkvb,
    const short* __restrict__ w2b,
    const float* __restrict__ pb,
    const float* __restrict__ comb,
    float* __restrict__ out)
{
  __shared__ __align__(16) short XB[32 * 136];   // x tile bf16; reused as AO
  __shared__ __align__(16) short QL[32 * 136];   // Q [token][d] (scaled)
  __shared__ __align__(16) short KL[32 * 136];   // K [token][d]
  __shared__ __align__(16) short VT[128 * 40];   // V^T [d][token]
  __shared__ __align__(16) short P[NH][32 * 48]; // softmax probs per head

  const int b = blockIdx.x;
  const int tid = threadIdx.x;
  const int wv = tid >> 6, l = tid & 63, l16 = l & 15, quad = l >> 4;
  floatx4 zero = {0.f, 0.f, 0.f, 0.f};

  // ---- Phase 1: stage x -> XB (bf16), zero pad rows 25..31 ----
  {
    const float* xsrc = x + (size_t)b * (NKEEP * DIM);
    for (int idx = tid; idx < 800; idx += 256) {       // 25 rows * 32 float4
      float4 v = reinterpret_cast<const float4*>(xsrc)[idx];
      const int row = idx >> 5, c = (idx & 31) * 4;
      short4 s;
      s.x = f2bs(v.x); s.y = f2bs(v.y); s.z = f2bs(v.z); s.w = f2bs(v.w);
      *reinterpret_cast<short4*>(&XB[row * 136 + c]) = s;
    }
    for (int idx = tid; idx < 224; idx += 256) {       // 7 pad rows * 32 short4
      const int row = 25 + (idx >> 5), c = (idx & 31) * 4;
      short4 z = {0, 0, 0, 0};
      *reinterpret_cast<short4*>(&XB[row * 136 + c]) = z;
    }
  }
  __syncthreads();

  // ---- Phase 2: QKV GEMM 32x384 (K=128), epilogue scatters to QL/KL/VT ----
  {
    const int obase = wv * 96;
    floatx4 acc[2][6];
#pragma unroll
    for (int mt = 0; mt < 2; ++mt)
#pragma unroll
      for (int nt = 0; nt < 6; ++nt) acc[mt][nt] = zero;

    bf16x8 a[2][4];
#pragma unroll
    for (int mt = 0; mt < 2; ++mt)
#pragma unroll
      for (int kk = 0; kk < 4; ++kk)
        a[mt][kk] = *reinterpret_cast<const bf16x8*>(
            &XB[(mt * 16 + l16) * 136 + kk * 32 + quad * 8]);

#pragma unroll
    for (int kk = 0; kk < 4; ++kk) {
      bf16x8 bw[6];
#pragma unroll
      for (int nt = 0; nt < 6; ++nt)
        bw[nt] = *reinterpret_cast<const bf16x8*>(
            w1b + (size_t)(obase + nt * 16 + l16) * DIM + kk * 32 + quad * 8);
#pragma unroll
      for (int nt = 0; nt < 6; ++nt)
#pragma unroll
        for (int mt = 0; mt < 2; ++mt)
          acc[mt][nt] = __builtin_amdgcn_mfma_f32_16x16x32_bf16(a[mt][kk], bw[nt], acc[mt][nt], 0, 0, 0);
    }

#pragma unroll
    for (int nt = 0; nt < 6; ++nt) {
      const int otile = obase + nt * 16;
      const int t = otile >> 7;         // 0=q 1=k 2=v (wave-uniform)
      const int c0 = otile & 127;
      const int o = otile + l16;
      const float bo = qkvb[o];
#pragma unroll
      for (int mt = 0; mt < 2; ++mt)
#pragma unroll
        for (int r = 0; r < 4; ++r) {
          const int m = mt * 16 + quad * 4 + r;
          const float v = acc[mt][nt][r] + bo;
          const int c = c0 + l16;
          if (t == 0)      QL[m * 136 + c] = f2bs(v * SCALE_Q);
          else if (t == 1) KL[m * 136 + c] = f2bs(v);
          else             VT[c * 40 + m] = f2bs(v);
        }
    }
  }
  __syncthreads();

  // ---- Phase 3: attention, head h = wv ----
  const int h = wv;
  {
    const int g = b & 63;
    const float* cb = comb + ((size_t)g * NH + h) * (NKEEP * NKEEP);

    bf16x8 aq[2], bk[2];
#pragma unroll
    for (int t = 0; t < 2; ++t) {
      aq[t] = *reinterpret_cast<const bf16x8*>(&QL[(t * 16 + l16) * 136 + h * 32 + quad * 8]);
      bk[t] = *reinterpret_cast<const bf16x8*>(&KL[(t * 16 + l16) * 136 + h * 32 + quad * 8]);
    }
    floatx4 S[2][2];
#pragma unroll
    for (int mt = 0; mt < 2; ++mt)
#pragma unroll
      for (int nt = 0; nt < 2; ++nt)
        S[mt][nt] = __builtin_amdgcn_mfma_f32_16x16x32_bf16(aq[mt], bk[nt], zero, 0, 0, 0);

#pragma unroll
    for (int mt = 0; mt < 2; ++mt) {
      float s[2][4];
#pragma unroll
      for (int nt = 0; nt < 2; ++nt)
#pragma unroll
        for (int r = 0; r < 4; ++r) {
          const int m = mt * 16 + quad * 4 + r;
          const int n = nt * 16 + l16;
          float v = S[mt][nt][r];
          if (n < 25) { if (m < 25) v += cb[m * 25 + n]; }
          else v = -1e30f;   // pad cols -> exp == 0 exactly
          s[nt][r] = v;
        }
#pragma unroll
      for (int r = 0; r < 4; ++r) {
        float mx = fmaxf(s[0][r], s[1][r]);
#pragma unroll
        for (int off = 1; off < 16; off <<= 1) mx = fmaxf(mx, __shfl_xor(mx, off));
        const float e0 = __expf(s[0][r] - mx);
        const float e1 = __expf(s[1][r] - mx);
        float sm = e0 + e1;
#pragma unroll
        for (int off = 1; off < 16; off <<= 1) sm += __shfl_xor(sm, off);
        const float inv = 1.f / sm;
        const int m = mt * 16 + quad * 4 + r;
        P[h][m * 48 + l16]      = f2bs(e0 * inv);
        P[h][m * 48 + 16 + l16] = f2bs(e1 * inv);
      }
    }

    bf16x8 ap[2], bv[2];
#pragma unroll
    for (int t = 0; t < 2; ++t) {
      ap[t] = *reinterpret_cast<const bf16x8*>(&P[h][(t * 16 + l16) * 48 + quad * 8]);
      bv[t] = *reinterpret_cast<const bf16x8*>(&VT[(h * 32 + t * 16 + l16) * 40 + quad * 8]);
    }
    floatx4 O[2][2];
#pragma unroll
    for (int mt = 0; mt < 2; ++mt)
#pragma unroll
      for (int nt = 0; nt < 2; ++nt)
        O[mt][nt] = __builtin_amdgcn_mfma_f32_16x16x32_bf16(ap[mt], bv[nt], zero, 0, 0, 0);

    // AO (union with XB): rows >=25 zeroed so proj A-frags are clean
#pragma unroll
    for (int mt = 0; mt < 2; ++mt)
#pragma unroll
      for (int r = 0; r < 4; ++r) {
        const int m = mt * 16 + quad * 4 + r;
#pragma unroll
        for (int nt = 0; nt < 2; ++nt)
          XB[m * 136 + h * 32 + nt * 16 + l16] = (m < 25) ? f2bs(O[mt][nt][r]) : (short)0;
      }
  }
  __syncthreads();

  // ---- Phase 4: proj, wave h -> out cols [h*32, h*32+32) ----
  {
    floatx4 acc2[2][2];
#pragma unroll
    for (int mt = 0; mt < 2; ++mt)
#pragma unroll
      for (int nt = 0; nt < 2; ++nt) acc2[mt][nt] = zero;

    bf16x8 a2[2][4];
#pragma unroll
    for (int mt = 0; mt < 2; ++mt)
#pragma unroll
      for (int kk = 0; kk < 4; ++kk)
        a2[mt][kk] = *reinterpret_cast<const bf16x8*>(
            &XB[(mt * 16 + l16) * 136 + kk * 32 + quad * 8]);

#pragma unroll
    for (int kk = 0; kk < 4; ++kk) {
      bf16x8 b2[2];
#pragma unroll
      for (int nt = 0; nt < 2; ++nt)
        b2[nt] = *reinterpret_cast<const bf16x8*>(
            w2b + (size_t)(h * 32 + nt * 16 + l16) * DIM + kk * 32 + quad * 8);
#pragma unroll
      for (int mt = 0; mt < 2; ++mt)
#pragma unroll
        for (int nt = 0; nt < 2; ++nt)
          acc2[mt][nt] = __builtin_amdgcn_mfma_f32_16x16x32_bf16(a2[mt][kk], b2[nt], acc2[mt][nt], 0, 0, 0);
    }

#pragma unroll
    for (int mt = 0; mt < 2; ++mt)
#pragma unroll
      for (int r = 0; r < 4; ++r) {
        const int m = mt * 16 + quad * 4 + r;
        if (m < 25) {
#pragma unroll
          for (int nt = 0; nt < 2; ++nt) {
            const int o = h * 32 + nt * 16 + l16;
            out[((size_t)b * NKEEP + m) * DIM + o] = acc2[mt][nt][r] + pb[o];
          }
        }
      }
  }
}

extern "C" void kernel_launch(void* const* d_in, const int* in_sizes, int n_in,
                              void* d_out, int out_size, void* d_ws, size_t ws_size,
                              hipStream_t stream) {
  const float* x    = (const float*)d_in[0];
  const float* mask = (const float*)d_in[1];
  const int*   ids  = (const int*)d_in[2];
  const float* qkvw = (const float*)d_in[3];
  const float* qkvb = (const float*)d_in[4];
  const float* pw   = (const float*)d_in[5];
  const float* pb   = (const float*)d_in[6];
  const float* btab = (const float*)d_in[7];
  const int*   rel  = (const int*)d_in[8];

  short* w1b  = (short*)d_ws;                     // 49152 shorts
  short* w2b  = w1b + 3 * DIM * DIM;              // 16384 shorts
  float* comb = (float*)(w2b + DIM * DIM);        // 160000 floats
  float* out  = (float*)d_out;

  k_cvtw <<<dim3(64),    256, 0, stream>>>(qkvw, pw, w1b, w2b);
  k_comb <<<dim3(625),   256, 0, stream>>>(mask, ids, rel, btab, comb);
  k_fused<<<dim3(B_TOT), 256, 0, stream>>>(x, w1b, qkvb, w2b, pb, comb, out);
}

// Round 5
// 210.924 us; speedup vs baseline: 1.1349x; 1.0141x over previous
//
#include <hip/hip_runtime.h>
#include <hip/hip_bf16.h>

typedef __attribute__((ext_vector_type(8))) short bf16x8;
typedef __attribute__((ext_vector_type(4))) float floatx4;

#define B_TOT 4096
#define NKEEP 25
#define DIM 128
#define NH 4
#define HD 32
#define SCALE_Q 0.17677669529663687f

__device__ __forceinline__ short f2bs(float f) {
  __hip_bfloat16 h = __float2bfloat16(f);
  return *reinterpret_cast<short*>(&h);
}

__device__ __forceinline__ bf16x8 ld8(const float* p) {
  const float4 u = reinterpret_cast<const float4*>(p)[0];
  const float4 v = reinterpret_cast<const float4*>(p)[1];
  bf16x8 r;
  r[0] = f2bs(u.x); r[1] = f2bs(u.y); r[2] = f2bs(u.z); r[3] = f2bs(u.w);
  r[4] = f2bs(v.x); r[5] = f2bs(v.y); r[6] = f2bs(v.z); r[7] = f2bs(v.w);
  return r;
}

// ---------------- Kernel A: prep = weight cvt (blocks 0..63) + comb (64..688)
__global__ __launch_bounds__(256) void k_prep(
    const float* __restrict__ w1, const float* __restrict__ w2,
    short* __restrict__ w1b, short* __restrict__ w2b,
    const float* __restrict__ mask,
    const int* __restrict__ ids,
    const int* __restrict__ rel,
    const float* __restrict__ btab,
    float* __restrict__ comb)
{
  const int blk = blockIdx.x;
  if (blk < 64) {
    const int t = blk * 256 + threadIdx.x;   // 16384 float4 groups exact
    const int G1 = 3 * DIM * DIM / 4;        // 12288
    const float* src; short* dst; int off;
    if (t < G1) { src = w1; dst = w1b; off = t; }
    else        { src = w2; dst = w2b; off = t - G1; }
    float4 v = reinterpret_cast<const float4*>(src)[off];
    short4 s;
    s.x = f2bs(v.x); s.y = f2bs(v.y); s.z = f2bs(v.z); s.w = f2bs(v.w);
    reinterpret_cast<short4*>(dst)[off] = s;
  } else {
    const int e = (blk - 64) * 256 + threadIdx.x;  // 160000 exact
    const int j = e % 25;
    const int i = (e / 25) % 25;
    const int h = (e / 625) & 3;
    const int g = e / 2500;
    const int ii = ids[g * 25 + i];
    const int jj = ids[g * 25 + j];
    const int ridx = rel[ii * 49 + jj];
    comb[e] = btab[ridx * 4 + h] + mask[((size_t)g * 49 + ii) * 49 + jj];
  }
}

// ---------------- Kernel B: fully fused QKV + attention + proj ----------
// One block per window. Wave wv: QKV cols [wv*96,wv*96+96); head wv; proj
// cols [wv*32,wv*32+32). x A-frags loaded directly from global (no staging).
__global__ __launch_bounds__(256, 4) void k_fused(
    const float* __restrict__ x,
    const short* __restrict__ w1b,
    const float* __restrict__ qkvb,
    const short* __restrict__ w2b,
    const float* __restrict__ pb,
    const float* __restrict__ comb,
    float* __restrict__ out)
{
  __shared__ __align__(16) short QA[32 * 136];   // Q (scaled) [token][d]; reused as AO
  __shared__ __align__(16) short KL[32 * 136];   // K [token][d]
  __shared__ __align__(16) short VT[128 * 40];   // V^T [d][token]
  __shared__ __align__(16) short P[NH][32 * 40]; // softmax probs per head

  const int b = blockIdx.x;
  const int tid = threadIdx.x;
  const int wv = tid >> 6, l = tid & 63, l16 = l & 15, quad = l >> 4;
  floatx4 zero = {0.f, 0.f, 0.f, 0.f};

  // ---- Phase 1: QKV GEMM, A direct from global x ----
  {
    const float* xb = x + (size_t)b * (NKEEP * DIM);
    bf16x8 a[2][4];
#pragma unroll
    for (int mt = 0; mt < 2; ++mt) {
      const int m = mt * 16 + l16;
      const int mc = m > 24 ? 24 : m;    // clamp: no OOB, dup rows masked later
      const float* rp = xb + mc * DIM;
#pragma unroll
      for (int kk = 0; kk < 4; ++kk)
        a[mt][kk] = ld8(rp + kk * 32 + quad * 8);
    }

    const int obase = wv * 96;
    floatx4 acc[2][6];
#pragma unroll
    for (int mt = 0; mt < 2; ++mt)
#pragma unroll
      for (int nt = 0; nt < 6; ++nt) acc[mt][nt] = zero;

#pragma unroll
    for (int kk = 0; kk < 4; ++kk) {
      bf16x8 bw[6];
#pragma unroll
      for (int nt = 0; nt < 6; ++nt)
        bw[nt] = *reinterpret_cast<const bf16x8*>(
            w1b + (size_t)(obase + nt * 16 + l16) * DIM + kk * 32 + quad * 8);
#pragma unroll
      for (int nt = 0; nt < 6; ++nt)
#pragma unroll
        for (int mt = 0; mt < 2; ++mt)
          acc[mt][nt] = __builtin_amdgcn_mfma_f32_16x16x32_bf16(a[mt][kk], bw[nt], acc[mt][nt], 0, 0, 0);
    }

#pragma unroll
    for (int nt = 0; nt < 6; ++nt) {
      const int otile = obase + nt * 16;
      const int t = otile >> 7;          // 0=q 1=k 2=v (wave-uniform)
      const int c0 = otile & 127;
      const float bo = qkvb[otile + l16];
      const int c = c0 + l16;
#pragma unroll
      for (int mt = 0; mt < 2; ++mt)
#pragma unroll
        for (int r = 0; r < 4; ++r) {
          const int m = mt * 16 + quad * 4 + r;
          const float v = acc[mt][nt][r] + bo;
          if (t == 0)      QA[m * 136 + c] = f2bs(v * SCALE_Q);
          else if (t == 1) KL[m * 136 + c] = f2bs(v);
          else             VT[c * 40 + m] = f2bs(v);
        }
    }
  }
  __syncthreads();

  // ---- Phase 2: attention, head h = wv ----
  const int h = wv;
  {
    const float* cb = comb + ((size_t)(b & 63) * NH + h) * (NKEEP * NKEEP);

    bf16x8 aq[2], bk[2];
#pragma unroll
    for (int t = 0; t < 2; ++t) {
      aq[t] = *reinterpret_cast<const bf16x8*>(&QA[(t * 16 + l16) * 136 + h * 32 + quad * 8]);
      bk[t] = *reinterpret_cast<const bf16x8*>(&KL[(t * 16 + l16) * 136 + h * 32 + quad * 8]);
    }
    floatx4 S[2][2];
#pragma unroll
    for (int mt = 0; mt < 2; ++mt)
#pragma unroll
      for (int nt = 0; nt < 2; ++nt)
        S[mt][nt] = __builtin_amdgcn_mfma_f32_16x16x32_bf16(aq[mt], bk[nt], zero, 0, 0, 0);

#pragma unroll
    for (int mt = 0; mt < 2; ++mt) {
      float s[2][4];
#pragma unroll
      for (int nt = 0; nt < 2; ++nt)
#pragma unroll
        for (int r = 0; r < 4; ++r) {
          const int m = mt * 16 + quad * 4 + r;
          const int n = nt * 16 + l16;
          float v = S[mt][nt][r];
          if (n < 25) { if (m < 25) v += cb[m * 25 + n]; }
          else v = -1e30f;   // pad cols -> exp == 0 exactly
          s[nt][r] = v;
        }
#pragma unroll
      for (int r = 0; r < 4; ++r) {
        float mx = fmaxf(s[0][r], s[1][r]);
#pragma unroll
        for (int off = 1; off < 16; off <<= 1) mx = fmaxf(mx, __shfl_xor(mx, off));
        const float e0 = __expf(s[0][r] - mx);
        const float e1 = __expf(s[1][r] - mx);
        float sm = e0 + e1;
#pragma unroll
        for (int off = 1; off < 16; off <<= 1) sm += __shfl_xor(sm, off);
        const float inv = 1.f / sm;
        const int m = mt * 16 + quad * 4 + r;
        P[h][m * 40 + l16]      = f2bs(e0 * inv);
        P[h][m * 40 + 16 + l16] = f2bs(e1 * inv);
      }
    }

    bf16x8 ap[2], bv[2];
#pragma unroll
    for (int t = 0; t < 2; ++t) {
      ap[t] = *reinterpret_cast<const bf16x8*>(&P[h][(t * 16 + l16) * 40 + quad * 8]);
      bv[t] = *reinterpret_cast<const bf16x8*>(&VT[(h * 32 + t * 16 + l16) * 40 + quad * 8]);
    }
    floatx4 O[2][2];
#pragma unroll
    for (int mt = 0; mt < 2; ++mt)
#pragma unroll
      for (int nt = 0; nt < 2; ++nt)
        O[mt][nt] = __builtin_amdgcn_mfma_f32_16x16x32_bf16(ap[mt], bv[nt], zero, 0, 0, 0);

    // AO unions with QA: wave h overwrites exactly the columns only it read.
#pragma unroll
    for (int mt = 0; mt < 2; ++mt)
#pragma unroll
      for (int r = 0; r < 4; ++r) {
        const int m = mt * 16 + quad * 4 + r;
#pragma unroll
        for (int nt = 0; nt < 2; ++nt)
          QA[m * 136 + h * 32 + nt * 16 + l16] = (m < 25) ? f2bs(O[mt][nt][r]) : (short)0;
      }
  }
  __syncthreads();

  // ---- Phase 3: proj, wave h -> out cols [h*32, h*32+32) ----
  {
    floatx4 acc2[2][2];
#pragma unroll
    for (int mt = 0; mt < 2; ++mt)
#pragma unroll
      for (int nt = 0; nt < 2; ++nt) acc2[mt][nt] = zero;

    bf16x8 a2[2][4];
#pragma unroll
    for (int mt = 0; mt < 2; ++mt)
#pragma unroll
      for (int kk = 0; kk < 4; ++kk)
        a2[mt][kk] = *reinterpret_cast<const bf16x8*>(
            &QA[(mt * 16 + l16) * 136 + kk * 32 + quad * 8]);

#pragma unroll
    for (int kk = 0; kk < 4; ++kk) {
      bf16x8 b2[2];
#pragma unroll
      for (int nt = 0; nt < 2; ++nt)
        b2[nt] = *reinterpret_cast<const bf16x8*>(
            w2b + (size_t)(h * 32 + nt * 16 + l16) * DIM + kk * 32 + quad * 8);
#pragma unroll
      for (int mt = 0; mt < 2; ++mt)
#pragma unroll
        for (int nt = 0; nt < 2; ++nt)
          acc2[mt][nt] = __builtin_amdgcn_mfma_f32_16x16x32_bf16(a2[mt][kk], b2[nt], acc2[mt][nt], 0, 0, 0);
    }

#pragma unroll
    for (int mt = 0; mt < 2; ++mt)
#pragma unroll
      for (int r = 0; r < 4; ++r) {
        const int m = mt * 16 + quad * 4 + r;
        if (m < 25) {
#pragma unroll
          for (int nt = 0; nt < 2; ++nt) {
            const int o = h * 32 + nt * 16 + l16;
            out[((size_t)b * NKEEP + m) * DIM + o] = acc2[mt][nt][r] + pb[o];
          }
        }
      }
  }
}

extern "C" void kernel_launch(void* const* d_in, const int* in_sizes, int n_in,
                              void* d_out, int out_size, void* d_ws, size_t ws_size,
                              hipStream_t stream) {
  const float* x    = (const float*)d_in[0];
  const float* mask = (const float*)d_in[1];
  const int*   ids  = (const int*)d_in[2];
  const float* qkvw = (const float*)d_in[3];
  const float* qkvb = (const float*)d_in[4];
  const float* pw   = (const float*)d_in[5];
  const float* pb   = (const float*)d_in[6];
  const float* btab = (const float*)d_in[7];
  const int*   rel  = (const int*)d_in[8];

  short* w1b  = (short*)d_ws;                     // 49152 shorts
  short* w2b  = w1b + 3 * DIM * DIM;              // 16384 shorts
  float* comb = (float*)(w2b + DIM * DIM);        // 160000 floats
  float* out  = (float*)d_out;

  k_prep <<<dim3(689),   256, 0, stream>>>(qkvw, pw, w1b, w2b, mask, ids, rel, btab, comb);
  k_fused<<<dim3(B_TOT), 256, 0, stream>>>(x, w1b, qkvb, w2b, pb, comb, out);
}

// Round 6
// 180.466 us; speedup vs baseline: 1.3264x; 1.1688x over previous
//
#include <hip/hip_runtime.h>
#include <hip/hip_bf16.h>

typedef __attribute__((ext_vector_type(8))) short bf16x8;
typedef __attribute__((ext_vector_type(4))) float floatx4;

#define B_TOT 4096
#define NKEEP 25
#define DIM 128
#define SCALE_Q 0.17677669529663687f

__device__ __forceinline__ short f2bs(float f) {
  __hip_bfloat16 h = __float2bfloat16(f);
  return *reinterpret_cast<short*>(&h);
}

__device__ __forceinline__ bf16x8 ld8(const float* p) {
  const float4 u = reinterpret_cast<const float4*>(p)[0];
  const float4 v = reinterpret_cast<const float4*>(p)[1];
  bf16x8 r;
  r[0] = f2bs(u.x); r[1] = f2bs(u.y); r[2] = f2bs(u.z); r[3] = f2bs(u.w);
  r[4] = f2bs(v.x); r[5] = f2bs(v.y); r[6] = f2bs(v.z); r[7] = f2bs(v.w);
  return r;
}

// ---------------- k_prep: swizzle everything into fragment order ----------
// xs  : per window, 512 chunks of 16B; chunk ((mt*4+kk)*64 + quad*16 + l16)
//       = x[win][clamp(mt*16+l16)][kk*32+quad*8 .. +8] as bf16
// w1s : chunk ((ot*4+kk)*64 + l) = w1[ot*16+l16][kk*32+quad*8..]  (ot 0..23)
// w2s : same with ot 0..7
// combs: [(g*4+h)*16 + mt*8+nt*4+r]*64 + quad*16+l16 = bias+mask at (m,n)
#define NXS  (2097152)   // 4096 * 512
#define NCB  (262144)    // 64 * 4 * 16 * 64
#define NW1  (6144)
#define NW2  (2048)

__global__ __launch_bounds__(256) void k_prep(
    const float* __restrict__ x, const float* __restrict__ w1,
    const float* __restrict__ w2, const float* __restrict__ mask,
    const int* __restrict__ ids, const int* __restrict__ rel,
    const float* __restrict__ btab,
    short* __restrict__ xs, short* __restrict__ w1s,
    short* __restrict__ w2s, float* __restrict__ combs)
{
  size_t t = (size_t)blockIdx.x * 256 + threadIdx.x;  // grid exactly covers
  if (t < NXS) {
    const int win = (int)(t >> 9), c = (int)(t & 511);
    const int i = c >> 6, l = c & 63;
    const int mt = i >> 2, kk = i & 3, quad = l >> 4, l16 = l & 15;
    int tok = mt * 16 + l16; if (tok > 24) tok = 24;
    const float* p = x + (size_t)win * (NKEEP * DIM) + tok * DIM + kk * 32 + quad * 8;
    *reinterpret_cast<bf16x8*>(xs + t * 8) = ld8(p);
  } else if (t < NXS + NCB) {
    const size_t u = t - NXS;
    const int g = (int)(u >> 12), rest = (int)(u & 4095);
    const int h = rest >> 10, j = rest & 1023;
    const int grp = j >> 6, lane = j & 63;
    const int mt = grp >> 3, nt = (grp >> 2) & 1, rr = grp & 3;
    const int quad = lane >> 4, l16 = lane & 15;
    const int m = mt * 16 + quad * 4 + rr, n = nt * 16 + l16;
    float v = 0.f;
    if (m < 25 && n < 25) {
      const int im = ids[g * 25 + m], in = ids[g * 25 + n];
      v = btab[rel[im * 49 + in] * 4 + h] + mask[((size_t)g * 49 + im) * 49 + in];
    }
    combs[u] = v;
  } else if (t < NXS + NCB + NW1) {
    const int c = (int)(t - (NXS + NCB));
    const int ot = c >> 8, rem = c & 255, kk = rem >> 6, l = rem & 63;
    const int quad = l >> 4, l16 = l & 15;
    *reinterpret_cast<bf16x8*>(w1s + (size_t)c * 8) =
        ld8(w1 + (size_t)(ot * 16 + l16) * DIM + kk * 32 + quad * 8);
  } else {
    const int c = (int)(t - (NXS + NCB + NW1));
    const int ot = c >> 8, rem = c & 255, kk = rem >> 6, l = rem & 63;
    const int quad = l >> 4, l16 = l & 15;
    *reinterpret_cast<bf16x8*>(w2s + (size_t)c * 8) =
        ld8(w2 + (size_t)(ot * 16 + l16) * DIM + kk * 32 + quad * 8);
  }
}

// ---------------- k_fused: 4 windows per block, weights in registers -------
// Block = 4 waves; wave h owns head h. Per round (window): QKV from XB
// (ping-pong staged) with w1 register fragments; attention wave-local in
// tiles T1/T2 (Q->VT->O, K->P); one barrier pair; proj from all 4 O tiles.
__global__ __launch_bounds__(256, 2) void k_fused(
    const short* __restrict__ xs, const short* __restrict__ w1s,
    const short* __restrict__ w2s, const float* __restrict__ qkvb,
    const float* __restrict__ pb, const float* __restrict__ combs,
    float* __restrict__ out)
{
  __shared__ __align__(16) short XB[8192];    // 2 x 512 chunks of 8 shorts
  __shared__ __align__(16) short TL[10240];   // 8 tiles of 32x40 shorts

  const int tid = threadIdx.x;
  const int wv = tid >> 6, l = tid & 63, l16 = l & 15, quad = l >> 4;
  const int h = wv;
  short* T1 = TL + wv * 2560;
  short* T2 = T1 + 1280;
  const int win0 = blockIdx.x * 4;
  const floatx4 zero = {0.f, 0.f, 0.f, 0.f};

  const int otl[6] = {2*h, 2*h+1, 8+2*h, 9+2*h, 16+2*h, 17+2*h};

  // persistent register weights + biases
  bf16x8 w1f[6][4];
#pragma unroll
  for (int t = 0; t < 6; ++t)
#pragma unroll
    for (int kk = 0; kk < 4; ++kk)
      w1f[t][kk] = *reinterpret_cast<const bf16x8*>(
          w1s + ((size_t)(otl[t] * 4 + kk) * 64 + l) * 8);
  float qb6[6];
#pragma unroll
  for (int t = 0; t < 6; ++t) qb6[t] = qkvb[otl[t] * 16 + l16];
  float pbf[2];
#pragma unroll
  for (int nt = 0; nt < 2; ++nt) pbf[nt] = pb[h * 32 + nt * 16 + l16];

  // stage window 0 into XB half 0
  {
    bf16x8 xg[2];
#pragma unroll
    for (int j = 0; j < 2; ++j) {
      const int c = wv * 128 + j * 64 + l;
      xg[j] = *reinterpret_cast<const bf16x8*>(xs + ((size_t)win0 * 512 + c) * 8);
    }
#pragma unroll
    for (int j = 0; j < 2; ++j) {
      const int c = wv * 128 + j * 64 + l;
      *reinterpret_cast<bf16x8*>(XB + c * 8) = xg[j];
    }
  }

  for (int r = 0; r < 4; ++r) {
    const int win = win0 + r;
    const int g = win & 63;

    // ---- prefetches (all coalesced, independent) ----
    bf16x8 xg[2];
    if (r < 3) {
#pragma unroll
      for (int j = 0; j < 2; ++j) {
        const int c = wv * 128 + j * 64 + l;
        xg[j] = *reinterpret_cast<const bf16x8*>(xs + ((size_t)(win + 1) * 512 + c) * 8);
      }
    }
    bf16x8 w2f[2][4];
#pragma unroll
    for (int nt = 0; nt < 2; ++nt)
#pragma unroll
      for (int kk = 0; kk < 4; ++kk)
        w2f[nt][kk] = *reinterpret_cast<const bf16x8*>(
            w2s + ((size_t)((h * 2 + nt) * 4 + kk) * 64 + l) * 8);
    float cmb[2][2][4];
#pragma unroll
    for (int mt = 0; mt < 2; ++mt)
#pragma unroll
      for (int nt = 0; nt < 2; ++nt)
#pragma unroll
        for (int rr = 0; rr < 4; ++rr)
          cmb[mt][nt][rr] =
              combs[(((size_t)g * 4 + h) * 16 + mt * 8 + nt * 4 + rr) * 64 + l];

    __syncthreads();   // barrier 1: prev round's proj reads done; XB visible

    // ---- QKV: A from XB (LDS), B from registers ----
    floatx4 acc[2][6];
#pragma unroll
    for (int mt = 0; mt < 2; ++mt)
#pragma unroll
      for (int t = 0; t < 6; ++t) acc[mt][t] = zero;
#pragma unroll
    for (int kk = 0; kk < 4; ++kk) {
      const bf16x8 a0 = *reinterpret_cast<const bf16x8*>(
          XB + ((r & 1) * 512 + kk * 64 + l) * 8);
      const bf16x8 a1 = *reinterpret_cast<const bf16x8*>(
          XB + ((r & 1) * 512 + (4 + kk) * 64 + l) * 8);
#pragma unroll
      for (int t = 0; t < 6; ++t) {
        acc[0][t] = __builtin_amdgcn_mfma_f32_16x16x32_bf16(a0, w1f[t][kk], acc[0][t], 0, 0, 0);
        acc[1][t] = __builtin_amdgcn_mfma_f32_16x16x32_bf16(a1, w1f[t][kk], acc[1][t], 0, 0, 0);
      }
    }
    // epilogue: Q -> T1 [tok][d], K -> T2 [tok][d], V kept in regs
    float vres[2][2][4];
#pragma unroll
    for (int t = 0; t < 2; ++t)
#pragma unroll
      for (int mt = 0; mt < 2; ++mt)
#pragma unroll
        for (int rr = 0; rr < 4; ++rr) {
          const int row = (mt * 16 + quad * 4 + rr) * 40 + t * 16 + l16;
          T1[row] = f2bs((acc[mt][t][rr] + qb6[t]) * SCALE_Q);
          T2[row] = f2bs(acc[mt][2 + t][rr] + qb6[2 + t]);
          vres[t][mt][rr] = acc[mt][4 + t][rr] + qb6[4 + t];
        }

    // ---- attention (wave-local) ----
    bf16x8 aq[2], bk[2];
#pragma unroll
    for (int t = 0; t < 2; ++t) {
      aq[t] = *reinterpret_cast<const bf16x8*>(&T1[(t * 16 + l16) * 40 + quad * 8]);
      bk[t] = *reinterpret_cast<const bf16x8*>(&T2[(t * 16 + l16) * 40 + quad * 8]);
    }
    floatx4 S[2][2];
#pragma unroll
    for (int mt = 0; mt < 2; ++mt)
#pragma unroll
      for (int nt = 0; nt < 2; ++nt)
        S[mt][nt] = __builtin_amdgcn_mfma_f32_16x16x32_bf16(aq[mt], bk[nt], zero, 0, 0, 0);

#pragma unroll
    for (int mt = 0; mt < 2; ++mt) {
      float s[2][4];
#pragma unroll
      for (int nt = 0; nt < 2; ++nt)
#pragma unroll
        for (int rr = 0; rr < 4; ++rr) {
          const int n = nt * 16 + l16;
          s[nt][rr] = (n < 25) ? S[mt][nt][rr] + cmb[mt][nt][rr] : -1e30f;
        }
#pragma unroll
      for (int rr = 0; rr < 4; ++rr) {
        float mx = fmaxf(s[0][rr], s[1][rr]);
#pragma unroll
        for (int off = 1; off < 16; off <<= 1) mx = fmaxf(mx, __shfl_xor(mx, off));
        const float e0 = __expf(s[0][rr] - mx);
        const float e1 = __expf(s[1][rr] - mx);
        float sm = e0 + e1;
#pragma unroll
        for (int off = 1; off < 16; off <<= 1) sm += __shfl_xor(sm, off);
        const float inv = 1.f / sm;
        const int row = (mt * 16 + quad * 4 + rr) * 40;
        T2[row + l16]      = f2bs(e0 * inv);   // P over K (K consumed)
        T2[row + 16 + l16] = f2bs(e1 * inv);
      }
    }
    // VT over Q in T1 (Q consumed): [d][tok], packed 4 tokens per store
#pragma unroll
    for (int t = 0; t < 2; ++t)
#pragma unroll
      for (int mt = 0; mt < 2; ++mt) {
        short4 pk;
        pk.x = f2bs(vres[t][mt][0]); pk.y = f2bs(vres[t][mt][1]);
        pk.z = f2bs(vres[t][mt][2]); pk.w = f2bs(vres[t][mt][3]);
        *reinterpret_cast<short4*>(&T1[(t * 16 + l16) * 40 + mt * 16 + quad * 4]) = pk;
      }
    bf16x8 ap[2], bv[2];
#pragma unroll
    for (int t = 0; t < 2; ++t) {
      ap[t] = *reinterpret_cast<const bf16x8*>(&T2[(t * 16 + l16) * 40 + quad * 8]);
      bv[t] = *reinterpret_cast<const bf16x8*>(&T1[(t * 16 + l16) * 40 + quad * 8]);
    }
    floatx4 O[2][2];
#pragma unroll
    for (int mt = 0; mt < 2; ++mt)
#pragma unroll
      for (int nt = 0; nt < 2; ++nt)
        O[mt][nt] = __builtin_amdgcn_mfma_f32_16x16x32_bf16(ap[mt], bv[nt], zero, 0, 0, 0);
    // O over VT in T1: [tok][d_local] (pad rows are garbage; only out rows
    // m<25 are stored, and M-dim rows are independent in the proj GEMM)
#pragma unroll
    for (int mt = 0; mt < 2; ++mt)
#pragma unroll
      for (int rr = 0; rr < 4; ++rr)
#pragma unroll
        for (int nt = 0; nt < 2; ++nt)
          T1[(mt * 16 + quad * 4 + rr) * 40 + nt * 16 + l16] = f2bs(O[mt][nt][rr]);

    // stage next window into the other XB half
    if (r < 3) {
#pragma unroll
      for (int j = 0; j < 2; ++j) {
        const int c = wv * 128 + j * 64 + l;
        *reinterpret_cast<bf16x8*>(XB + (((r + 1) & 1) * 512 + c) * 8) = xg[j];
      }
    }
    __syncthreads();   // barrier 2: all O tiles ready, XB staged

    // ---- proj: wave h -> out cols [h*32, h*32+32) ----
    floatx4 acc2[2][2];
#pragma unroll
    for (int mt = 0; mt < 2; ++mt)
#pragma unroll
      for (int nt = 0; nt < 2; ++nt) acc2[mt][nt] = zero;
#pragma unroll
    for (int kk = 0; kk < 4; ++kk) {
      const bf16x8 a20 = *reinterpret_cast<const bf16x8*>(
          &TL[kk * 2560 + (l16) * 40 + quad * 8]);
      const bf16x8 a21 = *reinterpret_cast<const bf16x8*>(
          &TL[kk * 2560 + (16 + l16) * 40 + quad * 8]);
#pragma unroll
      for (int nt = 0; nt < 2; ++nt) {
        acc2[0][nt] = __builtin_amdgcn_mfma_f32_16x16x32_bf16(a20, w2f[nt][kk], acc2[0][nt], 0, 0, 0);
        acc2[1][nt] = __builtin_amdgcn_mfma_f32_16x16x32_bf16(a21, w2f[nt][kk], acc2[1][nt], 0, 0, 0);
      }
    }
#pragma unroll
    for (int mt = 0; mt < 2; ++mt)
#pragma unroll
      for (int rr = 0; rr < 4; ++rr) {
        const int m = mt * 16 + quad * 4 + rr;
        if (m < 25) {
#pragma unroll
          for (int nt = 0; nt < 2; ++nt)
            out[((size_t)win * NKEEP + m) * DIM + h * 32 + nt * 16 + l16] =
                acc2[mt][nt][rr] + pbf[nt];
        }
      }
  }
}

extern "C" void kernel_launch(void* const* d_in, const int* in_sizes, int n_in,
                              void* d_out, int out_size, void* d_ws, size_t ws_size,
                              hipStream_t stream) {
  const float* x    = (const float*)d_in[0];
  const float* mask = (const float*)d_in[1];
  const int*   ids  = (const int*)d_in[2];
  const float* qkvw = (const float*)d_in[3];
  const float* qkvb = (const float*)d_in[4];
  const float* pw   = (const float*)d_in[5];
  const float* pb   = (const float*)d_in[6];
  const float* btab = (const float*)d_in[7];
  const int*   rel  = (const int*)d_in[8];

  short* xs    = (short*)d_ws;                        // 32 MB
  short* w1s   = xs + (size_t)NXS * 8;                // 96 KB
  short* w2s   = w1s + (size_t)NW1 * 8;               // 32 KB
  float* combs = (float*)(w2s + (size_t)NW2 * 8);     // 1 MB
  float* out   = (float*)d_out;

  const int prep_blocks = (NXS + NCB + NW1 + NW2) / 256;  // 9248
  k_prep <<<dim3(prep_blocks), 256, 0, stream>>>(
      x, qkvw, pw, mask, ids, rel, btab, xs, w1s, w2s, combs);
  k_fused<<<dim3(B_TOT / 4),   256, 0, stream>>>(
      xs, w1s, w2s, qkvb, pb, combs, out);
}